// Round 14
// baseline (90.349 us; speedup 1.0000x reference)
//
#include <hip/hip_runtime.h>

// Problem constants (fixed by reference)
#define CIN     32
#define COUT    64
#define OUT_DIM 1024
#define RS4     1024           // float4 per (.,c) row (4096 floats)

// out[b,o,p] = (1/sqrt(32)) * sum_{c,k} x[b,c,4p+k] * w[o,c,4p+k]
//
// v16 = v13 (best, 16.7 us kernel) + linear L3 prefetch. Evidence chain:
//   - v13/v14/v15: all scheduling levers (desync blocks, counted vmcnt)
//     failed; every tiling computes to 15-19 us at the observed ~3 TB/s
//     effective HBM rate -> the wall is DRAM efficiency of the scattered
//     256B-granule w read (linear sweeps measure 6.2-6.3 TB/s).
//   - v9-DIAG: allocation into L3 is clean (no dirty-victim writebacks)
//     and L3 retains the working set across reps (warm FETCH 11 MB).
// So: each block first sweeps a CONTIGUOUS 128 KB slice of w + 32 KB of x
// (chip-wide = linear 40 MB read ~6.7 us at full BW) into a discarded
// 1 KB LDS scratch via global_load_lds. First barrier drains it. The
// v13 pipeline (unchanged: o-tile 16, all 16 b, 4 c-chunks, double-
// buffered LDS, LDS-only compute) then runs L3-hot: per-chunk delivery
// ~1 us instead of ~2.5-3.5 -> expected kernel ~13-14 us.
__global__ __launch_bounds__(512, 2) void nolc1d_kernel(
    const float* __restrict__ x,
    const float* __restrict__ w,
    float* __restrict__ out)
{
    const int bid = blockIdx.x;
    const int xcd = bid & 7;
    const int m   = bid >> 3;               // 0..31
    const int og  = m & 3;                  // o-group 0..3 (16 o each)
    const int pc  = xcd * 8 + (m >> 2);     // patch-chunk 0..63 (16 p each)
    const int o0  = og * 16;
    const int pf0 = pc * 16;                // f4 (=patch) column base

    const int t    = threadIdx.x;           // = oq*128 + g*32 + cs*16 + p
    const int lane = t & 63;
    const int wv   = t >> 6;                // wave 0..7
    const int p    = t & 15;                // patch within chunk
    const int cs   = (t >> 4) & 1;          // c-split (2-way)
    const int g    = (t >> 5) & 3;          // b-quad (b = 4g+bi)
    const int oq   = t >> 7;                // o-quad (o = o0+4oq+oi)

    // [buf][(hi*8 + cl)*16 + q]: hi = ol (w) / b (x), cl = c within chunk,
    // q = f4 column. 2048 f4 = 32 KB each; 128 KB + 1 KB scratch.
    __shared__ float4 wls[2][2048];
    __shared__ float4 xls[2][2048];
    __shared__ float4 scratch[64];          // prefetch sink (data unused)

    const float4* __restrict__ x4 = (const float4*)x;
    const float4* __restrict__ w4 = (const float4*)w;

    // ---- L3 prefetch: linear sweep, contiguous slices per block.
    // w: 32 MB / 256 blocks = 128 KB = 8192 f4 (16 instrs/wave);
    // x:  8 MB / 256 blocks =  32 KB = 2048 f4 (4 instrs/wave).
    // Dest is the same 1 KB scratch every time (lane*16B appended by HW);
    // values are discarded -- the point is L3 allocation at full BW.
    {
        const float4* wpre = w4 + (size_t)bid * 8192;
        #pragma unroll
        for (int i = 0; i < 16; ++i) {
            const float4* src = wpre + (wv * 16 + i) * 64 + lane;
            __builtin_amdgcn_global_load_lds(
                (const __attribute__((address_space(1))) void*)src,
                (__attribute__((address_space(3))) void*)&scratch[0],
                16, 0, 0);
        }
        const float4* xpre = x4 + (size_t)bid * 2048;
        #pragma unroll
        for (int i = 0; i < 4; ++i) {
            const float4* src = xpre + (wv * 4 + i) * 64 + lane;
            __builtin_amdgcn_global_load_lds(
                (const __attribute__((address_space(1))) void*)src,
                (__attribute__((address_space(3))) void*)&scratch[0],
                16, 0, 0);
        }
    }

    const int r4 = lane >> 4;               // row within 4-row segment
    const int q  = lane & 15;

    // Stage c-chunk ci (c = 8ci..8ci+7) into buffer `buf`: per operand
    // 128 rows x 256 B = 32 KB = 32 wave-instrs (8 waves x 4). LDS dest is
    // wave-uniform base + lane*16 (linear); source rows 256 B contiguous.
    auto stage = [&](int buf, int ci) {
        #pragma unroll
        for (int i = 0; i < 4; ++i) {
            const int s   = wv * 4 + i;     // segment 0..31 (4 rows each)
            const int row = s * 4 + r4;     // 0..127 = hi*8 + cl
            const int hi  = row >> 3;
            const int c   = ci * 8 + (row & 7);
            const float4* srcw =
                &w4[((o0 + hi) * CIN + c) * RS4 + pf0 + q];
            __builtin_amdgcn_global_load_lds(
                (const __attribute__((address_space(1))) void*)srcw,
                (__attribute__((address_space(3))) void*)&wls[buf][s * 64],
                16, 0, 0);
            const float4* srcx =
                &x4[(hi * CIN + c) * RS4 + pf0 + q];
            __builtin_amdgcn_global_load_lds(
                (const __attribute__((address_space(1))) void*)srcx,
                (__attribute__((address_space(3))) void*)&xls[buf][s * 64],
                16, 0, 0);
        }
    };

    float acc[4][4] = {};                   // [bi][oi], carried over ci

    stage(0, 0);
    __syncthreads();   // drains prefetch + buffer 0 (each wave's own vmcnt)

    #pragma unroll 1
    for (int ci = 0; ci < 4; ++ci) {
        if (ci < 3) stage((ci + 1) & 1, ci + 1);   // async prefetch (L3-hot)
        const int buf = ci & 1;
        // compute: LDS only. This thread's c's: cl = cs*4 + jj.
        // w reads: 2-way same-address broadcast (free); x reads: 256 B
        // contiguous per 16 lanes -> no bank conflicts.
        #pragma unroll
        for (int jj = 0; jj < 4; ++jj) {
            const int cl = cs * 4 + jj;
            float4 xv[4], wq[4];
            #pragma unroll
            for (int bi = 0; bi < 4; ++bi)
                xv[bi] = xls[buf][((g * 4 + bi) * 8 + cl) * 16 + p];
            #pragma unroll
            for (int oi = 0; oi < 4; ++oi)
                wq[oi] = wls[buf][((oq * 4 + oi) * 8 + cl) * 16 + p];
            #pragma unroll
            for (int bi = 0; bi < 4; ++bi)
                #pragma unroll
                for (int oi = 0; oi < 4; ++oi)
                    acc[bi][oi] += xv[bi].x * wq[oi].x + xv[bi].y * wq[oi].y +
                                   xv[bi].z * wq[oi].z + xv[bi].w * wq[oi].w;
        }
        // readers done with buf (next iter's stage overwrites it) AND
        // prefetch for ci+1 drained. Not needed after last iter.
        if (ci < 3) __syncthreads();
    }

    // c-reduction: partner t^16 (same oq,g,p; cs^1) holds the other half.
    #pragma unroll
    for (int bi = 0; bi < 4; ++bi)
        #pragma unroll
        for (int oi = 0; oi < 4; ++oi)
            acc[bi][oi] += __shfl_xor(acc[bi][oi], 16, 64);

    const float scale = 0.17677669529663687f;  // 1/sqrt(32)
    if (cs == 0) {
        // lanes p=0..15 -> 64 B contiguous store per (bi,oi) per 16-lane
        // group; single writer per line.
        #pragma unroll
        for (int bi = 0; bi < 4; ++bi)
            #pragma unroll
            for (int oi = 0; oi < 4; ++oi)
                out[((size_t)(4 * g + bi) * COUT + o0 + 4 * oq + oi) * OUT_DIM
                    + pf0 + p] = acc[bi][oi] * scale;
    }
}

extern "C" void kernel_launch(void* const* d_in, const int* in_sizes, int n_in,
                              void* d_out, int out_size, void* d_ws, size_t ws_size,
                              hipStream_t stream) {
    const float* x = (const float*)d_in[0];   // [16][32][4096] fp32
    const float* w = (const float*)d_in[1];   // [64][32][4096] fp32
    float* out = (float*)d_out;               // [16][64][1024] fp32

    nolc1d_kernel<<<dim3(256), dim3(512), 0, stream>>>(x, w, out);
}

// Round 15
// 83.595 us; speedup vs baseline: 1.0808x; 1.0808x over previous
//
#include <hip/hip_runtime.h>

// Problem constants (fixed by reference)
#define CIN     32
#define COUT    64
#define OUT_DIM 1024
#define RS4     1024           // float4 per (.,c) row (4096 floats)

// out[b,o,p] = (1/sqrt(32)) * sum_{c,k} x[b,c,4p+k] * w[o,c,4p+k]
//
// v17: producer-consumer wave specialization -- ZERO barriers in the main
// loop. Evidence chain: v16 proved delivery time is residency-independent
// (L3 prefetch: +6.7 us, pipeline unchanged -> L3 fetch BW ~= HBM BW), so
// the residual wall is the barrier CONVOY: every chunk, all waves drain
// vmcnt(0) + s_barrier together; HBM demand is bursty (in-window 3.4 TB/s,
// average 2.6). Fix (the guide's named escape): 2 producer waves stream
// 8 c-chunks into 4 LDS buffer pairs, throttled by counted vmcnt(32)
// (<=48 outstanding < 63 cap) and consumer done-flags; 4 consumer waves
// spin on LDS flags and compute from LDS only. HBM demand is continuous,
// 2-3 chunks deep, no chip-wide breathing.
//   - geometry: v13's (o-tile 16, 16 patches, all 16 b; grid 256 = 4 og x
//     64 pc, XCD-swizzled so og-siblings share an XCD for x).
//   - each consumer thread owns (q, g, oq) for FULL K -> no reduction.
//   - x LDS layout XOR-swizzled by b-group (q' = q ^ (b>>2)) -> consumer
//     x reads conflict-free; w reads are 4-way broadcast (free).
//   - LDS: 4 x (16 KB w + 16 KB x) = 128 KB + flags.
__global__ __launch_bounds__(384, 2) void nolc1d_kernel(
    const float* __restrict__ x,
    const float* __restrict__ w,
    float* __restrict__ out)
{
    const int bid = blockIdx.x;
    const int xcd = bid & 7;
    const int m   = bid >> 3;               // 0..31
    const int og  = m & 3;                  // o-group 0..3 (16 o each)
    const int pc  = xcd * 8 + (m >> 2);     // patch-chunk 0..63 (16 p each)
    const int o0  = og * 16;
    const int pf0 = pc * 16;                // f4 (=patch) column base

    const int t    = threadIdx.x;
    const int lane = t & 63;
    const int wv   = t >> 6;                // wave 0..5

    // [buf][(hi*4 + cl)*16 + q]: hi = o-local (w) / b (x); cl = c within
    // chunk; q = f4 column (x stored at q^(b>>2)). 1024 f4 = 16 KB each.
    __shared__ float4 wls[4][1024];
    __shared__ float4 xls[4][1024];
    __shared__ int flag_w[8];
    __shared__ int flag_x[8];
    __shared__ int done[8];

    if (t < 8) { flag_w[t] = 0; flag_x[t] = 0; done[t] = 0; }
    __syncthreads();                        // the only barrier

    volatile int* vfw = flag_w;
    volatile int* vfx = flag_x;
    volatile int* vdn = done;

    const float4* __restrict__ x4 = (const float4*)x;
    const float4* __restrict__ w4 = (const float4*)w;

    if (wv == 0) {
        // ---- w producer: 16 x 1 KB gload_lds per chunk. Instr s: rows
        // (o-local=s, c = 4ci + lane>>4), cols q = lane&15 (4 x 256 B).
        const int cl = lane >> 4;
        const int q  = lane & 15;
        #pragma unroll 1
        for (int ci = 0; ci < 8; ++ci) {
            if (ci >= 4) while (vdn[ci - 4] < 4) __builtin_amdgcn_s_sleep(1);
            const int buf = ci & 3;
            #pragma unroll
            for (int s = 0; s < 16; ++s) {
                const float4* src =
                    &w4[((o0 + s) * CIN + ci * 4 + cl) * RS4 + pf0 + q];
                __builtin_amdgcn_global_load_lds(
                    (const __attribute__((address_space(1))) void*)src,
                    (__attribute__((address_space(3))) void*)&wls[buf][s * 64],
                    16, 0, 0);
            }
            if (ci >= 2) {                  // oldest chunk (ci-2) delivered
                asm volatile("s_waitcnt vmcnt(32)" ::: "memory");
                vfw[ci - 2] = 1;
            }
        }
        asm volatile("s_waitcnt vmcnt(16)" ::: "memory");
        vfw[6] = 1;
        asm volatile("s_waitcnt vmcnt(0)" ::: "memory");
        vfw[7] = 1;
    } else if (wv == 1) {
        // ---- x producer: same schedule; source q pre-swizzled so the
        // linear LDS slot q' holds global q = q' ^ (b>>2).
        const int cl = lane >> 4;
        #pragma unroll 1
        for (int ci = 0; ci < 8; ++ci) {
            if (ci >= 4) while (vdn[ci - 4] < 4) __builtin_amdgcn_s_sleep(1);
            const int buf = ci & 3;
            #pragma unroll
            for (int s = 0; s < 16; ++s) {
                const int qs = (lane & 15) ^ (s >> 2);
                const float4* src =
                    &x4[(s * CIN + ci * 4 + cl) * RS4 + pf0 + qs];
                __builtin_amdgcn_global_load_lds(
                    (const __attribute__((address_space(1))) void*)src,
                    (__attribute__((address_space(3))) void*)&xls[buf][s * 64],
                    16, 0, 0);
            }
            if (ci >= 2) {
                asm volatile("s_waitcnt vmcnt(32)" ::: "memory");
                vfx[ci - 2] = 1;
            }
        }
        asm volatile("s_waitcnt vmcnt(16)" ::: "memory");
        vfx[6] = 1;
        asm volatile("s_waitcnt vmcnt(0)" ::: "memory");
        vfx[7] = 1;
    } else {
        // ---- consumers: wave cw = wv-2 owns o-quad oq = cw; lane ->
        // (q = lane&15, g = lane>>4). Full K per thread: no reduction.
        const int cw = wv - 2;              // 0..3
        const int q  = lane & 15;
        const int g  = lane >> 4;           // b = 4g + bi
        float acc[4][4] = {};               // [bi][oi]

        #pragma unroll 1
        for (int ci = 0; ci < 8; ++ci) {
            while (vfw[ci] == 0) __builtin_amdgcn_s_sleep(1);
            while (vfx[ci] == 0) __builtin_amdgcn_s_sleep(1);
            const int buf = ci & 3;
            #pragma unroll
            for (int cl = 0; cl < 4; ++cl) {
                float4 xv[4], wq[4];
                #pragma unroll
                for (int bi = 0; bi < 4; ++bi)
                    xv[bi] = xls[buf][((g * 4 + bi) * 4 + cl) * 16 + (q ^ g)];
                #pragma unroll
                for (int oi = 0; oi < 4; ++oi)
                    wq[oi] = wls[buf][((cw * 4 + oi) * 4 + cl) * 16 + q];
                #pragma unroll
                for (int bi = 0; bi < 4; ++bi)
                    #pragma unroll
                    for (int oi = 0; oi < 4; ++oi)
                        acc[bi][oi] += xv[bi].x * wq[oi].x +
                                       xv[bi].y * wq[oi].y +
                                       xv[bi].z * wq[oi].z +
                                       xv[bi].w * wq[oi].w;
            }
            if (lane == 0) atomicAdd(&done[ci], 1);
        }

        const float scale = 0.17677669529663687f;  // 1/sqrt(32)
        #pragma unroll
        for (int bi = 0; bi < 4; ++bi)
            #pragma unroll
            for (int oi = 0; oi < 4; ++oi)
                out[((size_t)(4 * g + bi) * COUT + o0 + 4 * cw + oi) * OUT_DIM
                    + pf0 + q] = acc[bi][oi] * scale;
    }
}

extern "C" void kernel_launch(void* const* d_in, const int* in_sizes, int n_in,
                              void* d_out, int out_size, void* d_ws, size_t ws_size,
                              hipStream_t stream) {
    const float* x = (const float*)d_in[0];   // [16][32][4096] fp32
    const float* w = (const float*)d_in[1];   // [64][32][4096] fp32
    float* out = (float*)d_out;               // [16][64][1024] fp32

    nolc1d_kernel<<<dim3(256), dim3(384), 0, stream>>>(x, w, out);
}